// Round 21
// baseline (528.291 us; speedup 1.0000x reference)
//
#include <hip/hip_runtime.h>
#include <hip/hip_bf16.h>
#include <stdint.h>

typedef __attribute__((ext_vector_type(8))) short bf16x8;
typedef __attribute__((ext_vector_type(4))) float f32x4;
typedef __attribute__((ext_vector_type(4))) int i32x4;

constexpr int Mdim = 8192;
constexpr int Ndim = 11008;
constexpr int Kdim = 4096;
constexpr int NT = Kdim / 64;                       // 64 K-tiles of 64
constexpr int NMF = Mdim / 16;                      // 512 m-fraggroups
constexpr int NWG = (Mdim / 256) * (Ndim / 256);    // 1376
constexpr int CPX = NWG / 8;                        // 172
constexpr int NBN = Ndim / 256;                     // 43

__device__ __forceinline__ unsigned short f2bf(float f) {
    __bf16 h = (__bf16)f;
    return __builtin_bit_cast(unsigned short, h);
}

// ---------------- prepass 1 (fused): A fp32 -> i8 fragment-major  ||  per-col fold ----------------
// Af layout: [mf=m/16][kt=k/64] 1KB blocks; lane l holds row (mf*16 + l&15),
// k bytes kt*64 + (l>>4)*16 .. +15   (i8 MFMA A-frag order)
__global__ __launch_bounds__(256) void prepAS_kernel(const float* __restrict__ A,
                                                     char* __restrict__ Af,
                                                     float* __restrict__ sA,
                                                     const float* __restrict__ Ws,
                                                     float* __restrict__ Fc,
                                                     float* __restrict__ sCol)
{
    const int tid = threadIdx.x;
    if (blockIdx.x >= NMF) {
        const int n = ((int)blockIdx.x - NMF) * 256 + tid;   // 43*256 = 11008
        float mx = 0.f;
        for (int g = 0; g < 128; ++g) mx = fmaxf(mx, Ws[(size_t)g * Ndim + n]);
        Fc[n]   = 15.875f / mx;                              // 127/(8*mx)
        sCol[n] = mx * (8.0f / 127.0f);
        return;
    }
    __shared__ float sm[16][17];
    const int g = blockIdx.x;
    const int r   = tid >> 4;
    const int seg = tid & 15;
    const float* rowp = A + (size_t)(16 * g + r) * Kdim + seg * 256;
    float m = 0.f;
#pragma unroll 8
    for (int j = 0; j < 64; ++j) {
        const f32x4 v = *(const f32x4*)(rowp + j * 4);
#pragma unroll
        for (int e = 0; e < 4; ++e) m = fmaxf(m, fabsf(v[e]));
    }
    sm[r][seg] = m;
    __syncthreads();
    if (seg == 0) {
        float mo = 0.f;
#pragma unroll
        for (int i = 0; i < 16; ++i) mo = fmaxf(mo, sm[r][i]);
        sA[16 * g + r] = fmaxf(mo, 1e-20f) * (1.0f / 127.0f);
    }
    const int row = tid & 15;
    float mr = 0.f;
#pragma unroll
    for (int i = 0; i < 16; ++i) mr = fmaxf(mr, sm[row][i]);
    const float inv = 127.0f / fmaxf(mr, 1e-20f);
    const int l  = tid & 63;
    const int q  = tid >> 6;
    const int ch = l >> 4;
    const float* src0 = A + (size_t)(16 * g + row) * Kdim + ch * 16;
    char* dst0 = Af + (size_t)g * 65536 + (size_t)tid * 16;
#pragma unroll 4
    for (int it = 0; it < 16; ++it) {
        const int kt = it * 4 + q;
        const float* s = src0 + kt * 64;
        char o[16];
#pragma unroll
        for (int jj = 0; jj < 4; ++jj) {
            const f32x4 v = *(const f32x4*)(s + jj * 4);
#pragma unroll
            for (int e = 0; e < 4; ++e) o[jj * 4 + e] = (char)__float2int_rn(v[e] * inv);
        }
        *(i32x4*)(dst0 + it * 4096) = *(const i32x4*)o;
    }
}

// ---------------- prepass 2: W int4 -> i8 (scale-folded), fragment-major [nf][kt] ----------------
__global__ __launch_bounds__(256) void wq_kernel(const int* __restrict__ Wq,
                                                 const float* __restrict__ Ws,
                                                 const float* __restrict__ Fc,
                                                 char* __restrict__ Wf)
{
    __shared__ char T[64][80];
    const int kt = blockIdx.x % (Kdim / 64);
    const int nt = blockIdx.x / (Kdim / 64);
    const int k0 = kt * 64, n0 = nt * 64;
    const int t = threadIdx.x;

    const int pr   = t >> 3;
    const int nloc = (t & 7) * 8;
    const int* wp = Wq + (size_t)(k0 / 2 + pr) * Ndim + n0 + nloc;
    const i32x4 ra = *(const i32x4*)wp;
    const i32x4 rb = *(const i32x4*)(wp + 4);
    const int g = (k0 + 2 * pr) >> 5;
    const float* sp = Ws + (size_t)g * Ndim + n0 + nloc;
    const f32x4 s0 = *(const f32x4*)sp;
    const f32x4 s1 = *(const f32x4*)(sp + 4);
    const f32x4 f0 = *(const f32x4*)(Fc + n0 + nloc);
    const f32x4 f1 = *(const f32x4*)(Fc + n0 + nloc + 4);
#pragma unroll
    for (int i = 0; i < 8; ++i) {
        const int v = (i < 4) ? ra[i] : rb[i - 4];
        const float sf = ((i < 4) ? s0[i] : s1[i - 4]) * ((i < 4) ? f0[i] : f1[i - 4]);
        T[nloc + i][2 * pr]     = (char)__float2int_rn((float)((v & 15) - 8) * sf);
        T[nloc + i][2 * pr + 1] = (char)__float2int_rn((float)(((v >> 4) & 15) - 8) * sf);
    }
    __syncthreads();
    const int nl = t >> 2;
    const int ko = (t & 3) * 16;
    const i32x4 o = *(const i32x4*)&T[nl][ko];
    const int nf  = n0 / 16 + (nl >> 4);
    const int row = nl & 15;
    const int ch  = t & 3;
    *(i32x4*)(Wf + ((size_t)nf * 64 + kt) * 1024 + ch * 256 + row * 16) = o;
}

// ---- main GEMM: fully flat, 256x256 block, 8 waves x 128x64 (A 4x-shared, B 2x-shared) ----
__global__ __launch_bounds__(512, 2) void gemm_i8_flat(
    const char* __restrict__ Af,
    const char* __restrict__ Wf,
    const float* __restrict__ sA,
    const float* __restrict__ sCol,
    const float* __restrict__ Bias,
    float* __restrict__ Out)
{
    const int tid  = threadIdx.x;
    const int lane = tid & 63;
    const int wid  = tid >> 6;               // 0..7
    const int wr   = wid >> 2;               // 0..1 : M 128-row half
    const int wc   = wid & 3;                // 0..3 : N 64-col quarter
    const int l15  = lane & 15;
    const int l4   = lane >> 4;

    // XCD-aware bijective swizzle (1376 % 8 == 0), bm-major chunks per XCD
    const int wg  = ((int)blockIdx.x % 8) * CPX + (int)blockIdx.x / 8;
    const int bm = wg / NBN, bn = wg % NBN;
    const int m0 = bm * 256, n0 = bn * 256;

    // fragment stream bases (wave-uniform base + lane*16)
    const char* aBase = Af + ((size_t)(m0 / 16 + wr * 8) * 64) * 1024 + (lane << 4);
    const char* bBase = Wf + ((size_t)(n0 / 16 + wc * 4) * 64) * 1024 + (lane << 4);

#define LOADT(T, AV, BV)                                                      \
    {                                                                         \
        _Pragma("unroll")                                                     \
        for (int fm = 0; fm < 8; ++fm)                                        \
            AV[fm] = *(const i32x4*)(aBase + fm * 65536 + (T) * 1024);        \
        _Pragma("unroll")                                                     \
        for (int fn = 0; fn < 4; ++fn)                                        \
            BV[fn] = *(const i32x4*)(bBase + fn * 65536 + (T) * 1024);        \
    }

    i32x4 acc[8][4];
#pragma unroll
    for (int i = 0; i < 8; ++i)
#pragma unroll
        for (int j = 0; j < 4; ++j) acc[i][j] = (i32x4){0, 0, 0, 0};

    i32x4 aP[8], bP[4], aQ[8], bQ[4];
    LOADT(0, aP, bP);

#define TILE(T, CA, CB, NA, NB)                                               \
    {                                                                         \
        if ((T) + 1 < NT) LOADT((T) + 1, NA, NB);                             \
        __builtin_amdgcn_s_setprio(1);                                        \
        _Pragma("unroll")                                                     \
        for (int fm = 0; fm < 8; ++fm) {                                      \
            _Pragma("unroll")                                                 \
            for (int fn = 0; fn < 4; ++fn)                                    \
                acc[fm][fn] = __builtin_amdgcn_mfma_i32_16x16x64_i8(          \
                    CA[fm], CB[fn], acc[fm][fn], 0, 0, 0);                    \
        }                                                                     \
        __builtin_amdgcn_s_setprio(0);                                        \
    }

    for (int t2 = 0; t2 < NT; t2 += 2) {
        TILE(t2,     aP, bP, aQ, bQ);
        TILE(t2 + 1, aQ, bQ, aP, bP);
    }
#undef LOADT
#undef TILE

    // ---- epilogue: out = sA[m]*sCol[n]*acc + bias; C/D col=lane&15, row=(lane>>4)*4+r ----
    const int rb = l4 * 4;
    float sc[4], bb[4];
#pragma unroll
    for (int fn = 0; fn < 4; ++fn) {
        const int ng = n0 + wc * 64 + fn * 16 + l15;
        sc[fn] = sCol[ng];
        bb[fn] = Bias[ng];
    }
#pragma unroll
    for (int fm = 0; fm < 8; ++fm) {
        const size_t mg = (size_t)(m0 + wr * 128 + fm * 16 + rb);
#pragma unroll
        for (int r = 0; r < 4; ++r) {
            const float sa = sA[mg + r];
#pragma unroll
            for (int fn = 0; fn < 4; ++fn) {
                const int ng = n0 + wc * 64 + fn * 16 + l15;
                __builtin_nontemporal_store((float)acc[fm][fn][r] * sa * sc[fn] + bb[fn],
                                            &Out[(mg + r) * Ndim + ng]);
            }
        }
    }
}

// ---------------- fallback: fused bf16 kernel (if ws too small) ----------------
constexpr int SA = 72;
__global__ __launch_bounds__(256) void w4a32_fused_kernel(
    const float* __restrict__ A,
    const int* __restrict__ Wq,
    const float* __restrict__ Ws,
    const float* __restrict__ Bias,
    float* __restrict__ Out)
{
    __shared__ unsigned short As[128 * SA];
    __shared__ unsigned short Bs[128 * SA];
    const int tid = threadIdx.x;
    const int nbn = Ndim / 128;
    const int bn = blockIdx.x % nbn;
    const int bm = blockIdx.x / nbn;
    const int m0 = bm * 128, n0 = bn * 128;
    const int lane = tid & 63;
    const int wid  = tid >> 6;
    const int wr   = wid >> 1;
    const int wc   = wid & 1;
    const int l15  = lane & 15;
    const int l4   = lane >> 4;
    f32x4 acc[4][4];
#pragma unroll
    for (int i = 0; i < 4; ++i)
#pragma unroll
        for (int j = 0; j < 4; ++j) acc[i][j] = (f32x4){0.f, 0.f, 0.f, 0.f};
    const int a_tr = tid >> 3;
    const int a_tc = (tid & 7) * 8;
    const int kp2  = tid >> 4;
    const int n8   = (tid & 15) * 8;
    for (int kt = 0; kt < Kdim / 64; ++kt) {
        const int k0 = kt * 64;
        __syncthreads();
#pragma unroll
        for (int j = 0; j < 4; ++j) {
            const int ml = a_tr + 32 * j;
            const float* src = A + (size_t)(m0 + ml) * Kdim + (k0 + a_tc);
            const f32x4 x0 = *(const f32x4*)src;
            const f32x4 x1 = *(const f32x4*)(src + 4);
            union { bf16x8 v; unsigned short u[8]; } h;
            h.u[0] = f2bf(x0[0]); h.u[1] = f2bf(x0[1]);
            h.u[2] = f2bf(x0[2]); h.u[3] = f2bf(x0[3]);
            h.u[4] = f2bf(x1[0]); h.u[5] = f2bf(x1[1]);
            h.u[6] = f2bf(x1[2]); h.u[7] = f2bf(x1[3]);
            *(bf16x8*)(&As[ml * SA + (a_tc ^ ((ml & 7) << 3))]) = h.v;
        }
        {
            const int pr = kt * 32 + 2 * kp2;
            const int* wp = Wq + (size_t)pr * Ndim + (n0 + n8);
            const i32x4 r0a = *(const i32x4*)wp;
            const i32x4 r0b = *(const i32x4*)(wp + 4);
            const i32x4 r1a = *(const i32x4*)(wp + Ndim);
            const i32x4 r1b = *(const i32x4*)(wp + Ndim + 4);
            const int g = 2 * kt + (kp2 >> 3);
            const float* sp = Ws + (size_t)g * Ndim + (n0 + n8);
            const f32x4 s0 = *(const f32x4*)sp;
            const f32x4 s1 = *(const f32x4*)(sp + 4);
#pragma unroll
            for (int i = 0; i < 8; ++i) {
                const float s = (i < 4) ? s0[i] : s1[i - 4];
                const int b0 = (i < 4) ? r0a[i] : r0b[i - 4];
                const int b1 = (i < 4) ? r1a[i] : r1b[i - 4];
                union { unsigned long long v; unsigned short u[4]; } o;
                o.u[0] = f2bf((float)((b0 & 15) - 8) * s);
                o.u[1] = f2bf((float)(((b0 >> 4) & 15) - 8) * s);
                o.u[2] = f2bf((float)((b1 & 15) - 8) * s);
                o.u[3] = f2bf((float)(((b1 >> 4) & 15) - 8) * s);
                const int nl = n8 + i;
                const int swzz = ((nl ^ (nl >> 3)) & 7) << 3;
                *(unsigned long long*)(&Bs[nl * SA + ((4 * kp2) ^ swzz)]) = o.v;
            }
        }
        __syncthreads();
#pragma unroll
        for (int ks = 0; ks < 2; ++ks) {
            const int kb  = ks * 32 + l4 * 8;
            const int swa = (l15 & 7) << 3;
            bf16x8 af[4], bfr[4];
#pragma unroll
            for (int fm = 0; fm < 4; ++fm) {
                const int row = wr * 64 + fm * 16 + l15;
                af[fm] = *(const bf16x8*)(&As[row * SA + (kb ^ swa)]);
            }
#pragma unroll
            for (int fn = 0; fn < 4; ++fn) {
                const int nrow = wc * 64 + fn * 16 + l15;
                const int swb = ((nrow ^ (nrow >> 3)) & 7) << 3;
                bfr[fn] = *(const bf16x8*)(&Bs[nrow * SA + (kb ^ swb)]);
            }
#pragma unroll
            for (int fm = 0; fm < 4; ++fm)
#pragma unroll
                for (int fn = 0; fn < 4; ++fn)
                    acc[fm][fn] = __builtin_amdgcn_mfma_f32_16x16x32_bf16(
                        af[fm], bfr[fn], acc[fm][fn], 0, 0, 0);
        }
    }
    const int rb = l4 * 4;
    float bv[4];
#pragma unroll
    for (int fn = 0; fn < 4; ++fn)
        bv[fn] = Bias[n0 + wc * 64 + fn * 16 + l15];
#pragma unroll
    for (int fm = 0; fm < 4; ++fm) {
        const size_t mg = (size_t)(m0 + wr * 64 + fm * 16 + rb);
#pragma unroll
        for (int fn = 0; fn < 4; ++fn) {
            const int ng = n0 + wc * 64 + fn * 16 + l15;
            const float b = bv[fn];
#pragma unroll
            for (int r = 0; r < 4; ++r)
                Out[(mg + r) * Ndim + ng] = acc[fm][fn][r] + b;
        }
    }
}

extern "C" void kernel_launch(void* const* d_in, const int* in_sizes, int n_in,
                              void* d_out, int out_size, void* d_ws, size_t ws_size,
                              hipStream_t stream) {
    const float* A    = (const float*)d_in[0];
    const int* Wq     = (const int*)d_in[1];
    const float* Ws   = (const float*)d_in[2];
    const float* Bias = (const float*)d_in[3];
    float* Out        = (float*)d_out;

    const size_t offAf = 0;
    const size_t offWf = (size_t)Mdim * Kdim;                     // 33.5 MB
    const size_t offSA = offWf + (size_t)Ndim * Kdim;             // +45.1 MB
    const size_t offF  = offSA + (size_t)Mdim * 4;
    const size_t offSC = offF + (size_t)Ndim * 4;
    const size_t need  = offSC + (size_t)Ndim * 4;

    if (ws_size >= need) {
        char*  Af   = (char*)d_ws + offAf;
        char*  Wf   = (char*)d_ws + offWf;
        float* sAp  = (float*)((char*)d_ws + offSA);
        float* Fc   = (float*)((char*)d_ws + offF);
        float* sCol = (float*)((char*)d_ws + offSC);
        prepAS_kernel<<<NMF + Ndim / 256, 256, 0, stream>>>(A, Af, sAp, Ws, Fc, sCol);
        wq_kernel<<<(Kdim / 64) * (Ndim / 64), 256, 0, stream>>>(Wq, Ws, Fc, Wf);
        gemm_i8_flat<<<NWG, 512, 0, stream>>>(Af, Wf, sAp, sCol, Bias, Out);
    } else {
        w4a32_fused_kernel<<<(Mdim / 128) * (Ndim / 128), 256, 0, stream>>>(A, Wq, Ws, Bias, Out);
    }
}

// Round 22
// 472.077 us; speedup vs baseline: 1.1191x; 1.1191x over previous
//
#include <hip/hip_runtime.h>
#include <hip/hip_bf16.h>
#include <stdint.h>

typedef __attribute__((ext_vector_type(8))) short bf16x8;
typedef __attribute__((ext_vector_type(4))) float f32x4;
typedef __attribute__((ext_vector_type(4))) int i32x4;

constexpr int Mdim = 8192;
constexpr int Ndim = 11008;
constexpr int Kdim = 4096;
constexpr int NT = Kdim / 64;                       // 64 K-tiles of 64
constexpr int NMF = Mdim / 16;                      // 512 m-fraggroups
constexpr int NWG = (Mdim / 256) * (Ndim / 128);    // 2752
constexpr int CPX = NWG / 8;                        // 344
constexpr int NBN = Ndim / 128;                     // 86

__device__ __forceinline__ unsigned short f2bf(float f) {
    __bf16 h = (__bf16)f;
    return __builtin_bit_cast(unsigned short, h);
}

// ---------------- prepass 1 (fused): A fp32 -> i8 fragment-major  ||  per-col fold ----------------
// Af layout: [mf=m/16][kt=k/64] 1KB blocks; lane l holds row (mf*16 + l&15),
// k bytes kt*64 + (l>>4)*16 .. +15   (i8 MFMA A-frag order)
__global__ __launch_bounds__(256) void prepAS_kernel(const float* __restrict__ A,
                                                     char* __restrict__ Af,
                                                     float* __restrict__ sA,
                                                     const float* __restrict__ Ws,
                                                     float* __restrict__ Fc,
                                                     float* __restrict__ sCol)
{
    const int tid = threadIdx.x;
    if (blockIdx.x >= NMF) {
        const int n = ((int)blockIdx.x - NMF) * 256 + tid;   // 43*256 = 11008
        float mx = 0.f;
        for (int g = 0; g < 128; ++g) mx = fmaxf(mx, Ws[(size_t)g * Ndim + n]);
        Fc[n]   = 15.875f / mx;                              // 127/(8*mx)
        sCol[n] = mx * (8.0f / 127.0f);
        return;
    }
    __shared__ float sm[16][17];
    const int g = blockIdx.x;
    const int r   = tid >> 4;
    const int seg = tid & 15;
    const float* rowp = A + (size_t)(16 * g + r) * Kdim + seg * 256;
    float m = 0.f;
#pragma unroll 8
    for (int j = 0; j < 64; ++j) {
        const f32x4 v = *(const f32x4*)(rowp + j * 4);
#pragma unroll
        for (int e = 0; e < 4; ++e) m = fmaxf(m, fabsf(v[e]));
    }
    sm[r][seg] = m;
    __syncthreads();
    if (seg == 0) {
        float mo = 0.f;
#pragma unroll
        for (int i = 0; i < 16; ++i) mo = fmaxf(mo, sm[r][i]);
        sA[16 * g + r] = fmaxf(mo, 1e-20f) * (1.0f / 127.0f);
    }
    const int row = tid & 15;
    float mr = 0.f;
#pragma unroll
    for (int i = 0; i < 16; ++i) mr = fmaxf(mr, sm[row][i]);
    const float inv = 127.0f / fmaxf(mr, 1e-20f);
    const int l  = tid & 63;
    const int q  = tid >> 6;
    const int ch = l >> 4;
    const float* src0 = A + (size_t)(16 * g + row) * Kdim + ch * 16;
    char* dst0 = Af + (size_t)g * 65536 + (size_t)tid * 16;
#pragma unroll 4
    for (int it = 0; it < 16; ++it) {
        const int kt = it * 4 + q;
        const float* s = src0 + kt * 64;
        char o[16];
#pragma unroll
        for (int jj = 0; jj < 4; ++jj) {
            const f32x4 v = *(const f32x4*)(s + jj * 4);
#pragma unroll
            for (int e = 0; e < 4; ++e) o[jj * 4 + e] = (char)__float2int_rn(v[e] * inv);
        }
        *(i32x4*)(dst0 + it * 4096) = *(const i32x4*)o;
    }
}

// ---------------- prepass 2: W int4 -> i8 (scale-folded), fragment-major [nf][kt] ----------------
__global__ __launch_bounds__(256) void wq_kernel(const int* __restrict__ Wq,
                                                 const float* __restrict__ Ws,
                                                 const float* __restrict__ Fc,
                                                 char* __restrict__ Wf)
{
    __shared__ char T[64][80];
    const int kt = blockIdx.x % (Kdim / 64);
    const int nt = blockIdx.x / (Kdim / 64);
    const int k0 = kt * 64, n0 = nt * 64;
    const int t = threadIdx.x;

    const int pr   = t >> 3;
    const int nloc = (t & 7) * 8;
    const int* wp = Wq + (size_t)(k0 / 2 + pr) * Ndim + n0 + nloc;
    const i32x4 ra = *(const i32x4*)wp;
    const i32x4 rb = *(const i32x4*)(wp + 4);
    const int g = (k0 + 2 * pr) >> 5;
    const float* sp = Ws + (size_t)g * Ndim + n0 + nloc;
    const f32x4 s0 = *(const f32x4*)sp;
    const f32x4 s1 = *(const f32x4*)(sp + 4);
    const f32x4 f0 = *(const f32x4*)(Fc + n0 + nloc);
    const f32x4 f1 = *(const f32x4*)(Fc + n0 + nloc + 4);
#pragma unroll
    for (int i = 0; i < 8; ++i) {
        const int v = (i < 4) ? ra[i] : rb[i - 4];
        const float sf = ((i < 4) ? s0[i] : s1[i - 4]) * ((i < 4) ? f0[i] : f1[i - 4]);
        T[nloc + i][2 * pr]     = (char)__float2int_rn((float)((v & 15) - 8) * sf);
        T[nloc + i][2 * pr + 1] = (char)__float2int_rn((float)(((v >> 4) & 15) - 8) * sf);
    }
    __syncthreads();
    const int nl = t >> 2;
    const int ko = (t & 3) * 16;
    const i32x4 o = *(const i32x4*)&T[nl][ko];
    const int nf  = n0 / 16 + (nl >> 4);
    const int row = nl & 15;
    const int ch  = t & 3;
    *(i32x4*)(Wf + ((size_t)nf * 64 + kt) * 1024 + ch * 256 + row * 16) = o;
}

// ---- main GEMM: fully flat (no LDS, no barriers); 256x128 block, 4 waves x 128x64 ----
// bn-pairing: consecutive wg (same XCD) = bm-pair at SAME bn -> B panel shared via L2
__global__ __launch_bounds__(256, 2) void gemm_i8_flat(
    const char* __restrict__ Af,
    const char* __restrict__ Wf,
    const float* __restrict__ sA,
    const float* __restrict__ sCol,
    const float* __restrict__ Bias,
    float* __restrict__ Out)
{
    const int tid  = threadIdx.x;
    const int lane = tid & 63;
    const int wid  = tid >> 6;               // 0..3
    const int wr   = wid >> 1;               // 0..1 : M 128-row half
    const int wc   = wid & 1;                // 0..1 : N 64-col half
    const int l15  = lane & 15;
    const int l4   = lane >> 4;

    // XCD-aware bijective swizzle (2752 % 8 == 0); within-chunk: bm-PAIRS x bn
    const int wg  = ((int)blockIdx.x % 8) * CPX + (int)blockIdx.x / 8;
    const int p   = wg / (2 * NBN);          // 0..15 : bm pair-row
    const int r2  = wg % (2 * NBN);
    const int bm  = p * 2 + (r2 & 1);
    const int bn  = r2 >> 1;
    const int m0 = bm * 256, n0 = bn * 128;

    // fragment stream bases (wave-uniform base + lane*16)
    const char* aBase = Af + ((size_t)(m0 / 16 + wr * 8) * 64) * 1024 + (lane << 4);
    const char* bBase = Wf + ((size_t)(n0 / 16 + wc * 4) * 64) * 1024 + (lane << 4);

#define LOADT(T, AV, BV)                                                      \
    {                                                                         \
        _Pragma("unroll")                                                     \
        for (int fm = 0; fm < 8; ++fm)                                        \
            AV[fm] = *(const i32x4*)(aBase + fm * 65536 + (T) * 1024);        \
        _Pragma("unroll")                                                     \
        for (int fn = 0; fn < 4; ++fn)                                        \
            BV[fn] = *(const i32x4*)(bBase + fn * 65536 + (T) * 1024);        \
    }

    i32x4 acc[8][4];
#pragma unroll
    for (int i = 0; i < 8; ++i)
#pragma unroll
        for (int j = 0; j < 4; ++j) acc[i][j] = (i32x4){0, 0, 0, 0};

    i32x4 aP[8], bP[4], aQ[8], bQ[4];
    LOADT(0, aP, bP);

#define TILE(T, CA, CB, NA, NB)                                               \
    {                                                                         \
        if ((T) + 1 < NT) LOADT((T) + 1, NA, NB);                             \
        __builtin_amdgcn_s_setprio(1);                                        \
        _Pragma("unroll")                                                     \
        for (int fm = 0; fm < 8; ++fm) {                                      \
            _Pragma("unroll")                                                 \
            for (int fn = 0; fn < 4; ++fn)                                    \
                acc[fm][fn] = __builtin_amdgcn_mfma_i32_16x16x64_i8(          \
                    CA[fm], CB[fn], acc[fm][fn], 0, 0, 0);                    \
        }                                                                     \
        __builtin_amdgcn_s_setprio(0);                                        \
    }

    for (int t2 = 0; t2 < NT; t2 += 2) {
        TILE(t2,     aP, bP, aQ, bQ);
        TILE(t2 + 1, aQ, bQ, aP, bP);
    }
#undef LOADT
#undef TILE

    // ---- epilogue: out = sA[m]*sCol[n]*acc + bias; C/D col=lane&15, row=(lane>>4)*4+r ----
    const int rb = l4 * 4;
    float sc[4], bb[4];
#pragma unroll
    for (int fn = 0; fn < 4; ++fn) {
        const int ng = n0 + wc * 64 + fn * 16 + l15;
        sc[fn] = sCol[ng];
        bb[fn] = Bias[ng];
    }
#pragma unroll
    for (int fm = 0; fm < 8; ++fm) {
        const size_t mg = (size_t)(m0 + wr * 128 + fm * 16 + rb);
#pragma unroll
        for (int r = 0; r < 4; ++r) {
            const float sa = sA[mg + r];
#pragma unroll
            for (int fn = 0; fn < 4; ++fn) {
                const int ng = n0 + wc * 64 + fn * 16 + l15;
                __builtin_nontemporal_store((float)acc[fm][fn][r] * sa * sc[fn] + bb[fn],
                                            &Out[(mg + r) * Ndim + ng]);
            }
        }
    }
}

// ---------------- fallback: fused bf16 kernel (if ws too small) ----------------
constexpr int SA = 72;
__global__ __launch_bounds__(256) void w4a32_fused_kernel(
    const float* __restrict__ A,
    const int* __restrict__ Wq,
    const float* __restrict__ Ws,
    const float* __restrict__ Bias,
    float* __restrict__ Out)
{
    __shared__ unsigned short As[128 * SA];
    __shared__ unsigned short Bs[128 * SA];
    const int tid = threadIdx.x;
    const int nbn = Ndim / 128;
    const int bn = blockIdx.x % nbn;
    const int bm = blockIdx.x / nbn;
    const int m0 = bm * 128, n0 = bn * 128;
    const int lane = tid & 63;
    const int wid  = tid >> 6;
    const int wr   = wid >> 1;
    const int wc   = wid & 1;
    const int l15  = lane & 15;
    const int l4   = lane >> 4;
    f32x4 acc[4][4];
#pragma unroll
    for (int i = 0; i < 4; ++i)
#pragma unroll
        for (int j = 0; j < 4; ++j) acc[i][j] = (f32x4){0.f, 0.f, 0.f, 0.f};
    const int a_tr = tid >> 3;
    const int a_tc = (tid & 7) * 8;
    const int kp2  = tid >> 4;
    const int n8   = (tid & 15) * 8;
    for (int kt = 0; kt < Kdim / 64; ++kt) {
        const int k0 = kt * 64;
        __syncthreads();
#pragma unroll
        for (int j = 0; j < 4; ++j) {
            const int ml = a_tr + 32 * j;
            const float* src = A + (size_t)(m0 + ml) * Kdim + (k0 + a_tc);
            const f32x4 x0 = *(const f32x4*)src;
            const f32x4 x1 = *(const f32x4*)(src + 4);
            union { bf16x8 v; unsigned short u[8]; } h;
            h.u[0] = f2bf(x0[0]); h.u[1] = f2bf(x0[1]);
            h.u[2] = f2bf(x0[2]); h.u[3] = f2bf(x0[3]);
            h.u[4] = f2bf(x1[0]); h.u[5] = f2bf(x1[1]);
            h.u[6] = f2bf(x1[2]); h.u[7] = f2bf(x1[3]);
            *(bf16x8*)(&As[ml * SA + (a_tc ^ ((ml & 7) << 3))]) = h.v;
        }
        {
            const int pr = kt * 32 + 2 * kp2;
            const int* wp = Wq + (size_t)pr * Ndim + (n0 + n8);
            const i32x4 r0a = *(const i32x4*)wp;
            const i32x4 r0b = *(const i32x4*)(wp + 4);
            const i32x4 r1a = *(const i32x4*)(wp + Ndim);
            const i32x4 r1b = *(const i32x4*)(wp + Ndim + 4);
            const int g = 2 * kt + (kp2 >> 3);
            const float* sp = Ws + (size_t)g * Ndim + (n0 + n8);
            const f32x4 s0 = *(const f32x4*)sp;
            const f32x4 s1 = *(const f32x4*)(sp + 4);
#pragma unroll
            for (int i = 0; i < 8; ++i) {
                const float s = (i < 4) ? s0[i] : s1[i - 4];
                const int b0 = (i < 4) ? r0a[i] : r0b[i - 4];
                const int b1 = (i < 4) ? r1a[i] : r1b[i - 4];
                union { unsigned long long v; unsigned short u[4]; } o;
                o.u[0] = f2bf((float)((b0 & 15) - 8) * s);
                o.u[1] = f2bf((float)(((b0 >> 4) & 15) - 8) * s);
                o.u[2] = f2bf((float)((b1 & 15) - 8) * s);
                o.u[3] = f2bf((float)(((b1 >> 4) & 15) - 8) * s);
                const int nl = n8 + i;
                const int swzz = ((nl ^ (nl >> 3)) & 7) << 3;
                *(unsigned long long*)(&Bs[nl * SA + ((4 * kp2) ^ swzz)]) = o.v;
            }
        }
        __syncthreads();
#pragma unroll
        for (int ks = 0; ks < 2; ++ks) {
            const int kb  = ks * 32 + l4 * 8;
            const int swa = (l15 & 7) << 3;
            bf16x8 af[4], bfr[4];
#pragma unroll
            for (int fm = 0; fm < 4; ++fm) {
                const int row = wr * 64 + fm * 16 + l15;
                af[fm] = *(const bf16x8*)(&As[row * SA + (kb ^ swa)]);
            }
#pragma unroll
            for (int fn = 0; fn < 4; ++fn) {
                const int nrow = wc * 64 + fn * 16 + l15;
                const int swb = ((nrow ^ (nrow >> 3)) & 7) << 3;
                bfr[fn] = *(const bf16x8*)(&Bs[nrow * SA + (kb ^ swb)]);
            }
#pragma unroll
            for (int fm = 0; fm < 4; ++fm)
#pragma unroll
                for (int fn = 0; fn < 4; ++fn)
                    acc[fm][fn] = __builtin_amdgcn_mfma_f32_16x16x32_bf16(
                        af[fm], bfr[fn], acc[fm][fn], 0, 0, 0);
        }
    }
    const int rb = l4 * 4;
    float bv[4];
#pragma unroll
    for (int fn = 0; fn < 4; ++fn)
        bv[fn] = Bias[n0 + wc * 64 + fn * 16 + l15];
#pragma unroll
    for (int fm = 0; fm < 4; ++fm) {
        const size_t mg = (size_t)(m0 + wr * 64 + fm * 16 + rb);
#pragma unroll
        for (int fn = 0; fn < 4; ++fn) {
            const int ng = n0 + wc * 64 + fn * 16 + l15;
            const float b = bv[fn];
#pragma unroll
            for (int r = 0; r < 4; ++r)
                Out[(mg + r) * Ndim + ng] = acc[fm][fn][r] + b;
        }
    }
}

extern "C" void kernel_launch(void* const* d_in, const int* in_sizes, int n_in,
                              void* d_out, int out_size, void* d_ws, size_t ws_size,
                              hipStream_t stream) {
    const float* A    = (const float*)d_in[0];
    const int* Wq     = (const int*)d_in[1];
    const float* Ws   = (const float*)d_in[2];
    const float* Bias = (const float*)d_in[3];
    float* Out        = (float*)d_out;

    const size_t offAf = 0;
    const size_t offWf = (size_t)Mdim * Kdim;                     // 33.5 MB
    const size_t offSA = offWf + (size_t)Ndim * Kdim;             // +45.1 MB
    const size_t offF  = offSA + (size_t)Mdim * 4;
    const size_t offSC = offF + (size_t)Ndim * 4;
    const size_t need  = offSC + (size_t)Ndim * 4;

    if (ws_size >= need) {
        char*  Af   = (char*)d_ws + offAf;
        char*  Wf   = (char*)d_ws + offWf;
        float* sAp  = (float*)((char*)d_ws + offSA);
        float* Fc   = (float*)((char*)d_ws + offF);
        float* sCol = (float*)((char*)d_ws + offSC);
        prepAS_kernel<<<NMF + Ndim / 256, 256, 0, stream>>>(A, Af, sAp, Ws, Fc, sCol);
        wq_kernel<<<(Kdim / 64) * (Ndim / 64), 256, 0, stream>>>(Wq, Ws, Fc, Wf);
        gemm_i8_flat<<<NWG, 256, 0, stream>>>(Af, Wf, sAp, sCol, Bias, Out);
    } else {
        w4a32_fused_kernel<<<(Mdim / 128) * (Ndim / 128), 256, 0, stream>>>(A, Wq, Ws, Bias, Out);
    }
}